// Round 10
// baseline (177.771 us; speedup 1.0000x reference)
//
#include <hip/hip_runtime.h>
#include <math.h>

// Problem constants
#define BB 4
#define CIN 64
#define COUT 64
#define HH 128
#define WW 128
#define HW (HH*WW)

typedef __attribute__((ext_vector_type(8))) short short8;   // 8 bf16 = 4 VGPRs
typedef __attribute__((ext_vector_type(4))) float f32x4;
typedef __attribute__((ext_vector_type(2))) float f32x2;
typedef __attribute__((ext_vector_type(4))) unsigned int uint4v;

static __device__ __forceinline__ unsigned short f2bf(float f) {
    unsigned int u = __builtin_bit_cast(unsigned int, f);
    u += 0x7fffu + ((u >> 16) & 1u);          // round-to-nearest-even
    return (unsigned short)(u >> 16);
}
static __device__ __forceinline__ float bf2f(unsigned short h) {
    unsigned int u = ((unsigned int)h) << 16;
    return __builtin_bit_cast(float, u);
}
// pack 2 f32 -> 2 bf16 in one HW instruction (RNE, == f2bf on finite vals)
static __device__ __forceinline__ unsigned int cvtpk_bf16(float lo, float hi) {
    unsigned int r;
    asm("v_cvt_pk_bf16_f32 %0, %1, %2" : "=v"(r) : "v"(lo), "v"(hi));
    return r;
}
// unpack 2 bf16 from a u32 into float2 (2 inst)
static __device__ __forceinline__ f32x2 bfpair(unsigned int u) {
    f32x2 r;
    r[0] = __builtin_bit_cast(float, u << 16);
    r[1] = __builtin_bit_cast(float, u & 0xffff0000u);
    return r;
}

// ---------------------------------------------------------------------------
// K1: wkpack (80 blocks) + bias2 (1 block).  Tiny; everything else moved out.
// ---------------------------------------------------------------------------
__global__ __launch_bounds__(256) void prep_kernel(
        const float* __restrict__ com_w, const float* __restrict__ c2w,
        const float* __restrict__ bias,
        unsigned short* __restrict__ wk2, float* __restrict__ bias2) {
    int id = blockIdx.x, tid = threadIdx.x;
    if (id < 80) {
        int i = id*256 + tid;               // < 20480
        int k = i & 31, oc = (i >> 5) & 31;
        int cc5 = i >> 10;                  // cg*5 + chunk
        int cg = cc5 / 5, ch = cc5 % 5;
        int tap = ch*2 + (k >> 4);
        int c = cg*16 + (k & 15);
        float v = 0.f;
        if (tap < 9 && oc < 27) v = com_w[((size_t)oc*64 + c)*9 + tap];
        wk2[i] = f2bf(v);
    } else if (tid < COUT) {
        float s2 = 0.f;
        for (int o = 0; o < COUT; ++o) s2 += c2w[tid*COUT + o] * bias[o];
        bias2[tid] = s2;
    }
}

// ---------------------------------------------------------------------------
// channel-last bf16 transpose of one (b, 64-px strip): src[b][c][px]->dst[b][px][c]
// ---------------------------------------------------------------------------
static __device__ __forceinline__ void transpose_body(
        const float* __restrict__ srcb, unsigned short* __restrict__ dstb,
        int tb, int tid, float* lt /* 64*65 floats */) {
    int b = tb >> 8;
    int px0 = (tb & 255) * 64;
    const float* src = srcb + (size_t)b*CIN*HW + px0;
    for (int i = tid; i < 4096; i += 256) {
        int c = i >> 6, px = i & 63;
        lt[c*65 + px] = src[(size_t)c*HW + px];
    }
    __syncthreads();
    int q = tid & 3, px = tid >> 2;
    unsigned short* dst = dstb + ((size_t)b*HW + px0 + px)*64 + q*16;
    #pragma unroll
    for (int s = 0; s < 2; ++s) {
        short8 pk;
        #pragma unroll
        for (int j = 0; j < 8; ++j)
            pk[j] = (short)f2bf(lt[(q*16 + s*8 + j)*65 + px]);
        *(short8*)(dst + s*8) = pk;
    }
}

// ---------------------------------------------------------------------------
// w2 with INLINE fvec (wave-reduced): W2b[b][p][o2][c] bf16 (MFMA A layout)
// Unswizzled: dcn reads A-frags directly from global (L1/L2-hot).
// ---------------------------------------------------------------------------
static __device__ __forceinline__ void w2_body(
        int wid, int tid, const float* __restrict__ weight,
        const float* __restrict__ c2w, const float* __restrict__ c1w,
        const float* __restrict__ fea,
        unsigned short* __restrict__ w2b, float* c2s, float* wcol) {
    int o2 = tid & 63, ci = tid >> 6;
    int lane = tid & 63;
    int bp = wid >> 4;
    int c_base = (wid & 15)*4;
    int p = bp % 9, b = bp / 9;
    int c = c_base + ci;

    // inline fvec[b][c] for this wave's c: 4 MAC/lane + wave reduce
    float part = 0.f;
    #pragma unroll
    for (int s = 0; s < 4; ++s)
        part += c1w[c*(4*CIN) + lane + s*64] * fea[b*(4*CIN) + lane + s*64];
    #pragma unroll
    for (int off = 32; off; off >>= 1) part += __shfl_down(part, off);
    float fv = __shfl(part, 0);

    for (int idx = tid; idx < 4096; idx += 256) {
        int o2r = idx >> 6, oc = idx & 63;
        c2s[oc*65 + o2r] = c2w[idx];
    }
    {
        int o = tid & 63, cw = tid >> 6;
        wcol[cw*64 + o] = weight[(o*CIN + (c_base + cw))*9 + p];
    }
    __syncthreads();
    float s = 0.f;
    #pragma unroll 8
    for (int o = 0; o < COUT; ++o) s += c2s[o*65 + o2] * wcol[ci*64 + o];
    w2b[(size_t)bp*4096 + o2*64 + c] = f2bf(s * fv);
}

// ---------------------------------------------------------------------------
// conv v2 (round-4-proven): 512 blocks = b(4) x by(16) x bx(8); tile = 8 rows
// x 16 px, ALL 27 output channels per block (B-tile staged ONCE, each ds_read
// feeds 2 MFMAs).  Division-free branch-free staging.
// ---------------------------------------------------------------------------
static __device__ __forceinline__ void conv_lds_body(
        int id, int tid, const float* __restrict__ inter,
        const unsigned short* __restrict__ wk2, const float* __restrict__ com_b,
        float* __restrict__ om, float* smemf) {
    unsigned short* til = (unsigned short*)smemf;   // [182][24] shorts (8736B)
    int b  = id >> 7;          // 0..3
    int t7 = id & 127;
    int by = t7 >> 3;          // 0..15
    int bx = t7 & 7;           // 0..7
    int x0 = bx*16, y0 = by*8;
    int lane = tid & 63, wv = tid >> 6;
    int nn = lane & 15, qq = lane >> 4;

    // zero the dummy px row (180) once; staging never overwrites it
    if (tid < 24) til[180*24 + tid] = 0;

    // staging coords fixed per thread: cl = tid&15, cc = tid>>4 (0..15)
    int scl = tid & 15, scc = tid >> 4;
    int sgx  = x0 + scc - 1;
    int sgxc = max(sgx, 0);                 // <= 126, always in-bounds
    float sfx = ((unsigned)sgx < WW) ? 1.f : 0.f;

    f32x4 acc[2][2];
    #pragma unroll
    for (int nt = 0; nt < 2; ++nt)
        #pragma unroll
        for (int mh = 0; mh < 2; ++mh)
            #pragma unroll
            for (int j = 0; j < 4; ++j) acc[nt][mh][j] = 0.f;

    for (int cg = 0; cg < 4; ++cg) {
        __syncthreads();                    // previous cg's reads done
        const float* I = inter + ((size_t)(b*CIN + cg*16))*HW;

        // main staging: rows r=0..9, cc=0..15 (2560 elems, 10/thread)
        {
            const float* colp = I + (size_t)scl*HW + sgxc;
            unsigned short* tp = til + scc*24 + scl;
            #pragma unroll
            for (int r = 0; r < 10; ++r) {
                int gy  = y0 + r - 1;
                int gyc = min(max(gy, 0), HH-1);
                float m = ((unsigned)gy < HH) ? sfx : 0.f;
                float v = colp[(size_t)gyc*WW] * m;
                tp[r*(18*24)] = f2bf(v);
            }
        }
        // tail staging: cc=16,17 (320 elems), i = r*32 + ccb*16 + cl
        #pragma unroll
        for (int k = 0; k < 2; ++k) {
            int i = k*256 + tid;
            if (i < 320) {
                int cl  = i & 15;
                int ccb = (i >> 4) & 1;         // cc = 16+ccb
                int r   = i >> 5;               // 0..9
                int gx  = x0 + 15 + ccb;
                int gy  = y0 + r - 1;
                int gxc = min(gx, WW-1);
                int gyc = min(max(gy, 0), HH-1);
                float m = (((unsigned)gy < HH) && ((unsigned)gx < WW)) ? 1.f : 0.f;
                float v = I[(size_t)cl*HW + gyc*WW + gxc] * m;
                til[(r*18 + 16 + ccb)*24 + cl] = f2bf(v);
            }
        }
        __syncthreads();

        #pragma unroll
        for (int ch = 0; ch < 5; ++ch) {
            short8 a0 = *(const short8*)(wk2 +
                (((size_t)(cg*5 + ch)*32 + nn)*32 + qq*8));
            short8 a1 = *(const short8*)(wk2 +
                (((size_t)(cg*5 + ch)*32 + 16 + nn)*32 + qq*8));
            int tap = ch*2 + (qq >> 1);
            #pragma unroll
            for (int nt = 0; nt < 2; ++nt) {
                int row = wv*2 + nt;            // 0..7
                int px_idx;
                if (tap > 8) px_idx = 180;
                else {
                    int ky = tap/3, kx = tap%3;
                    px_idx = (row + ky)*18 + (nn + kx);
                }
                short8 bfr = *(const short8*)(til + px_idx*24 + (qq&1)*8);
                acc[nt][0] = __builtin_amdgcn_mfma_f32_16x16x32_bf16(
                                 a0, bfr, acc[nt][0], 0, 0, 0);
                acc[nt][1] = __builtin_amdgcn_mfma_f32_16x16x32_bf16(
                                 a1, bfr, acc[nt][1], 0, 0, 0);
            }
        }
    }

    float* op = om + (size_t)b*27*HW;
    #pragma unroll
    for (int nt = 0; nt < 2; ++nt) {
        int pix = (y0 + wv*2 + nt)*WW + x0 + nn;
        #pragma unroll
        for (int mh = 0; mh < 2; ++mh)
            #pragma unroll
            for (int j = 0; j < 4; ++j) {
                int oc = mh*16 + qq*4 + j;
                if (oc < 27)
                    op[(size_t)oc*HW + pix] = acc[nt][mh][j] + com_b[oc];
            }
    }
}

// ---------------------------------------------------------------------------
// K2: conv (512) + w2 (576) + fT transpose (1024) = 2112 blocks
// ---------------------------------------------------------------------------
__global__ __launch_bounds__(256) void main2_kernel(
        const float* __restrict__ input_feat,
        const float* __restrict__ inter,
        const unsigned short* __restrict__ wk2,
        const float* __restrict__ com_b,
        const float* __restrict__ weight,
        const float* __restrict__ c2w,
        const float* __restrict__ c1w,
        const float* __restrict__ fea,
        float* __restrict__ om, unsigned short* __restrict__ w2b,
        unsigned short* __restrict__ fT) {
    __shared__ __align__(16) float smem[4416];
    int id = blockIdx.x, tid = threadIdx.x;
    if (id < 512)        conv_lds_body(id, tid, inter, wk2, com_b, om, smem);
    else if (id < 1088)  w2_body(id - 512, tid, weight, c2w, c1w, fea, w2b,
                                 smem, smem + 64*65);
    else                 transpose_body(input_feat, fT, id - 1088, tid, smem);
}

// ---------------------------------------------------------------------------
// K3: main DCN GEMM, bf16 MFMA.
// v9: MERGED-K — one wave owns a 16-px strip END-TO-END (full K=64).
// R0-R9 established: VALUBusy x dur ~ constant (~2000 us*%), and half the
// scalar work (bilinear weights, om loads, sigmoid, gather addresses) was
// computed TWICE by the kh=0/kh=1 split-K wave pair.  Merging:
//  * one bilinear chain per strip-tap (was two) -> ~28% chip VALU cut;
//  * 8 gathers read both 64B halves of the SAME 128B fT line back-to-back
//    (2nd is a guaranteed L1 hit — R4's lockstep benefit, now intra-wave);
//  * ZERO shared memory, ZERO barriers, no split-K reduce epilogue;
//  * om traffic halved (each pixel's offsets read once, not twice);
//  * 1024 blocks = 4/CU, 4096 waves fully resident in one generation.
// fp32 accumulation order changes only by reorder (bias + interleaved lo/hi
// vs split-then-add) — ~1e-6 relative, invisible at bf16 tolerance.
// XCD batch-binding kept: xcd = blk&7, b = xcd>>1 (FETCH 13.6 -> 8.1 MB).
// ---------------------------------------------------------------------------
__global__ __launch_bounds__(256) void dcn_main_kernel(
        const unsigned short* __restrict__ fT,
        const unsigned short* __restrict__ w2b,
        const float* __restrict__ bias2,
        const float* __restrict__ om,
        float* __restrict__ out) {
    int id = blockIdx.x;                 // 0..1023
    int xcd = id & 7;                    // round-robin XCD assignment
    int b   = xcd >> 1;                  // 2 XCDs per batch -> per-XCD L2 fit
    int xh  = xcd & 1;                   // which 64-px half-row
    int y   = id >> 3;                   // 0..127

    int t = threadIdx.x;
    int lane = t & 63, wv = t >> 6;
    int nn = lane & 15, qq = lane >> 4;
    int px0 = xh*64 + wv*16;             // wave's 16-px strip
    int x = px0 + nn;
    int pix = y*WW + x;
    const unsigned short* Fb = fT + (size_t)b*HW*64;
    const float* omb = om + (size_t)b*27*HW;
    const unsigned short* w2p = w2b + (size_t)(b*9)*4096 + qq*8;
    int co = qq*8;                       // lo-half channel offset; hi = +32

    f32x4 acc[4];
    #pragma unroll
    for (int mt = 0; mt < 4; ++mt)
        #pragma unroll
        for (int j = 0; j < 4; ++j)
            acc[mt][j] = bias2[mt*16 + qq*4 + j];

    float omy = omb[pix];
    float omx = omb[(size_t)HW + pix];
    float omm = omb[(size_t)18*HW + pix];

    #pragma unroll
    for (int p = 0; p < 9; ++p) {
        // A-frags, both K-halves (tiny, L1/L2-hot)
        short8 afrL[4], afrH[4];
        #pragma unroll
        for (int mt = 0; mt < 4; ++mt) {
            const unsigned short* ap = w2p + (size_t)p*4096 + (mt*16 + nn)*64;
            afrL[mt] = *(const short8*)(ap);
            afrH[mt] = *(const short8*)(ap + 32);
        }

        // bilinear corner weights for my pixel (computed ONCE per strip now)
        float mv = 1.f / (1.f + expf(-omm));
        float ysv = (float)(y - 1 + p/3) + omy;
        float xsv = (float)(x - 1 + p%3) + omx;
        float y0f = floorf(ysv), x0f = floorf(xsv);
        float ly = ysv - y0f, lx = xsv - x0f;
        int y0 = (int)y0f, x0i = (int)x0f;
        int y1 = y0 + 1, x1 = x0i + 1;
        float vy0 = (y0 >= 0 && y0 < HH) ? 1.f : 0.f;
        float vy1 = (y1 >= 0 && y1 < HH) ? 1.f : 0.f;
        float vx0 = (x0i >= 0 && x0i < WW) ? 1.f : 0.f;
        float vx1 = (x1 >= 0 && x1 < WW) ? 1.f : 0.f;
        float w00 = (1.f-ly)*(1.f-lx)*mv * vy0*vx0;
        float w01 = (1.f-ly)*lx      *mv * vy0*vx1;
        float w10 = ly      *(1.f-lx)*mv * vy1*vx0;
        float w11 = ly      *lx      *mv * vy1*vx1;
        int y0c = min(max(y0,0),HH-1), y1c = min(max(y1,0),HH-1);
        int x0c = min(max(x0i,0),WW-1), x1c = min(max(x1,0),WW-1);
        int i00 = y0c*WW + x0c, i01 = y0c*WW + x1c;
        int i10 = y1c*WW + x0c, i11 = y1c*WW + x1c;

        // prefetch next p's om
        if (p < 8) {
            omy = omb[(size_t)(2*p+2)*HW + pix];
            omx = omb[(size_t)(2*p+3)*HW + pix];
            omm = omb[(size_t)(19+p )*HW + pix];
        }

        // gather 4 corners x 2 K-halves; the +32 (64B) load of each pair
        // lands in the same 128B line -> L1 hit (offset folds into the
        // instruction's immediate, no extra address math)
        const unsigned short* p00 = Fb + (size_t)i00*64 + co;
        const unsigned short* p01 = Fb + (size_t)i01*64 + co;
        const unsigned short* p10 = Fb + (size_t)i10*64 + co;
        const unsigned short* p11 = Fb + (size_t)i11*64 + co;
        short8 c00L = *(const short8*)(p00);
        short8 c01L = *(const short8*)(p01);
        short8 c10L = *(const short8*)(p10);
        short8 c11L = *(const short8*)(p11);
        short8 c00H = *(const short8*)(p00 + 32);
        short8 c01H = *(const short8*)(p01 + 32);
        short8 c10H = *(const short8*)(p10 + 32);
        short8 c11H = *(const short8*)(p11 + 32);

        // pack lo half: f32x2 weighted sum + v_cvt_pk_bf16_f32
        uint4v u00 = __builtin_bit_cast(uint4v, c00L);
        uint4v u01 = __builtin_bit_cast(uint4v, c01L);
        uint4v u10 = __builtin_bit_cast(uint4v, c10L);
        uint4v u11 = __builtin_bit_cast(uint4v, c11L);
        unsigned int pw[4];
        #pragma unroll
        for (int jp = 0; jp < 4; ++jp) {
            f32x2 A = bfpair(u00[jp]);
            f32x2 B = bfpair(u01[jp]);
            f32x2 C = bfpair(u10[jp]);
            f32x2 D = bfpair(u11[jp]);
            f32x2 r = A*w00 + B*w01 + C*w10 + D*w11;
            pw[jp] = cvtpk_bf16(r[0], r[1]);
        }
        uint4v u4L = {pw[0], pw[1], pw[2], pw[3]};
        short8 bfrL = __builtin_bit_cast(short8, u4L);
        #pragma unroll
        for (int mt = 0; mt < 4; ++mt)
            acc[mt] = __builtin_amdgcn_mfma_f32_16x16x32_bf16(
                          afrL[mt], bfrL, acc[mt], 0, 0, 0);

        // pack hi half
        u00 = __builtin_bit_cast(uint4v, c00H);
        u01 = __builtin_bit_cast(uint4v, c01H);
        u10 = __builtin_bit_cast(uint4v, c10H);
        u11 = __builtin_bit_cast(uint4v, c11H);
        #pragma unroll
        for (int jp = 0; jp < 4; ++jp) {
            f32x2 A = bfpair(u00[jp]);
            f32x2 B = bfpair(u01[jp]);
            f32x2 C = bfpair(u10[jp]);
            f32x2 D = bfpair(u11[jp]);
            f32x2 r = A*w00 + B*w01 + C*w10 + D*w11;
            pw[jp] = cvtpk_bf16(r[0], r[1]);
        }
        uint4v u4H = {pw[0], pw[1], pw[2], pw[3]};
        short8 bfrH = __builtin_bit_cast(short8, u4H);
        #pragma unroll
        for (int mt = 0; mt < 4; ++mt)
            acc[mt] = __builtin_amdgcn_mfma_f32_16x16x32_bf16(
                          afrH[mt], bfrH, acc[mt], 0, 0, 0);
    }

    // direct write — no split-K partner, no LDS, no barrier
    float* outp = out + (size_t)b*COUT*HW + (size_t)y*WW + px0 + nn;
    #pragma unroll
    for (int mt = 0; mt < 4; ++mt)
        #pragma unroll
        for (int j = 0; j < 4; ++j)
            outp[(size_t)(mt*16 + qq*4 + j)*HW] = acc[mt][j];
}

// ---------------------------------------------------------------------------
extern "C" void kernel_launch(void* const* d_in, const int* in_sizes, int n_in,
                              void* d_out, int out_size, void* d_ws, size_t ws_size,
                              hipStream_t stream) {
    const float* input_feat = (const float*)d_in[0];
    const float* inter      = (const float*)d_in[1];
    const float* fea        = (const float*)d_in[2];
    const float* weight     = (const float*)d_in[3];
    const float* bias       = (const float*)d_in[4];
    const float* com_w      = (const float*)d_in[5];
    const float* com_b      = (const float*)d_in[6];
    const float* c1w        = (const float*)d_in[7];
    const float* c2w        = (const float*)d_in[8];
    float* out = (float*)d_out;

    float* ws    = (float*)d_ws;
    float* bias2 = ws + 256;                               // 64 (in pad area)
    unsigned short* w2b = (unsigned short*)(ws + 512);     // 147456 us
    float* om    = ws + 512 + 73728;                       // 1769472 f
    unsigned short* wk2 = (unsigned short*)(om + 1769472); // 20480 us
    unsigned short* fT  = wk2 + 20480;                     // 4194304 us

    prep_kernel<<<81, 256, 0, stream>>>(com_w, c2w, bias, wk2, bias2);
    main2_kernel<<<2112, 256, 0, stream>>>(input_feat, inter, wk2, com_b,
                                           weight, c2w, c1w, fea, om, w2b, fT);
    dcn_main_kernel<<<1024, 256, 0, stream>>>(fT, w2b, bias2, om, out);
}

// Round 12
// 163.448 us; speedup vs baseline: 1.0876x; 1.0876x over previous
//
#include <hip/hip_runtime.h>
#include <math.h>

// Problem constants
#define BB 4
#define CIN 64
#define COUT 64
#define HH 128
#define WW 128
#define HW (HH*WW)

typedef __attribute__((ext_vector_type(8))) short short8;   // 8 bf16 = 4 VGPRs
typedef __attribute__((ext_vector_type(4))) float f32x4;
typedef __attribute__((ext_vector_type(2))) float f32x2;
typedef __attribute__((ext_vector_type(4))) unsigned int uint4v;

static __device__ __forceinline__ unsigned short f2bf(float f) {
    unsigned int u = __builtin_bit_cast(unsigned int, f);
    u += 0x7fffu + ((u >> 16) & 1u);          // round-to-nearest-even
    return (unsigned short)(u >> 16);
}
static __device__ __forceinline__ float bf2f(unsigned short h) {
    unsigned int u = ((unsigned int)h) << 16;
    return __builtin_bit_cast(float, u);
}
// pack 2 f32 -> 2 bf16 in one HW instruction (RNE, == f2bf on finite vals)
static __device__ __forceinline__ unsigned int cvtpk_bf16(float lo, float hi) {
    unsigned int r;
    asm("v_cvt_pk_bf16_f32 %0, %1, %2" : "=v"(r) : "v"(lo), "v"(hi));
    return r;
}
// unpack 2 bf16 from a u32 into float2 (2 inst)
static __device__ __forceinline__ f32x2 bfpair(unsigned int u) {
    f32x2 r;
    r[0] = __builtin_bit_cast(float, u << 16);
    r[1] = __builtin_bit_cast(float, u & 0xffff0000u);
    return r;
}

// ---------------------------------------------------------------------------
// K1: wkpack (80 blocks) + bias2 (1 block).  Tiny; everything else moved out.
// ---------------------------------------------------------------------------
__global__ __launch_bounds__(256) void prep_kernel(
        const float* __restrict__ com_w, const float* __restrict__ c2w,
        const float* __restrict__ bias,
        unsigned short* __restrict__ wk2, float* __restrict__ bias2) {
    int id = blockIdx.x, tid = threadIdx.x;
    if (id < 80) {
        int i = id*256 + tid;               // < 20480
        int k = i & 31, oc = (i >> 5) & 31;
        int cc5 = i >> 10;                  // cg*5 + chunk
        int cg = cc5 / 5, ch = cc5 % 5;
        int tap = ch*2 + (k >> 4);
        int c = cg*16 + (k & 15);
        float v = 0.f;
        if (tap < 9 && oc < 27) v = com_w[((size_t)oc*64 + c)*9 + tap];
        wk2[i] = f2bf(v);
    } else if (tid < COUT) {
        float s2 = 0.f;
        for (int o = 0; o < COUT; ++o) s2 += c2w[tid*COUT + o] * bias[o];
        bias2[tid] = s2;
    }
}

// ---------------------------------------------------------------------------
// channel-last bf16 transpose of one (b, 64-px strip): src[b][c][px]->dst[b][px][c]
// ---------------------------------------------------------------------------
static __device__ __forceinline__ void transpose_body(
        const float* __restrict__ srcb, unsigned short* __restrict__ dstb,
        int tb, int tid, float* lt /* 64*65 floats */) {
    int b = tb >> 8;
    int px0 = (tb & 255) * 64;
    const float* src = srcb + (size_t)b*CIN*HW + px0;
    for (int i = tid; i < 4096; i += 256) {
        int c = i >> 6, px = i & 63;
        lt[c*65 + px] = src[(size_t)c*HW + px];
    }
    __syncthreads();
    int q = tid & 3, px = tid >> 2;
    unsigned short* dst = dstb + ((size_t)b*HW + px0 + px)*64 + q*16;
    #pragma unroll
    for (int s = 0; s < 2; ++s) {
        short8 pk;
        #pragma unroll
        for (int j = 0; j < 8; ++j)
            pk[j] = (short)f2bf(lt[(q*16 + s*8 + j)*65 + px]);
        *(short8*)(dst + s*8) = pk;
    }
}

// ---------------------------------------------------------------------------
// w2 with INLINE fvec (wave-reduced): W2b[b][p][o2][c] bf16 (MFMA A layout)
// Unswizzled: dcn reads A-frags directly from global (L1/L2-hot).
// ---------------------------------------------------------------------------
static __device__ __forceinline__ void w2_body(
        int wid, int tid, const float* __restrict__ weight,
        const float* __restrict__ c2w, const float* __restrict__ c1w,
        const float* __restrict__ fea,
        unsigned short* __restrict__ w2b, float* c2s, float* wcol) {
    int o2 = tid & 63, ci = tid >> 6;
    int lane = tid & 63;
    int bp = wid >> 4;
    int c_base = (wid & 15)*4;
    int p = bp % 9, b = bp / 9;
    int c = c_base + ci;

    // inline fvec[b][c] for this wave's c: 4 MAC/lane + wave reduce
    float part = 0.f;
    #pragma unroll
    for (int s = 0; s < 4; ++s)
        part += c1w[c*(4*CIN) + lane + s*64] * fea[b*(4*CIN) + lane + s*64];
    #pragma unroll
    for (int off = 32; off; off >>= 1) part += __shfl_down(part, off);
    float fv = __shfl(part, 0);

    for (int idx = tid; idx < 4096; idx += 256) {
        int o2r = idx >> 6, oc = idx & 63;
        c2s[oc*65 + o2r] = c2w[idx];
    }
    {
        int o = tid & 63, cw = tid >> 6;
        wcol[cw*64 + o] = weight[(o*CIN + (c_base + cw))*9 + p];
    }
    __syncthreads();
    float s = 0.f;
    #pragma unroll 8
    for (int o = 0; o < COUT; ++o) s += c2s[o*65 + o2] * wcol[ci*64 + o];
    w2b[(size_t)bp*4096 + o2*64 + c] = f2bf(s * fv);
}

// ---------------------------------------------------------------------------
// conv v2 (round-4-proven): 512 blocks = b(4) x by(16) x bx(8); tile = 8 rows
// x 16 px, ALL 27 output channels per block (B-tile staged ONCE, each ds_read
// feeds 2 MFMAs).  Division-free branch-free staging.
// ---------------------------------------------------------------------------
static __device__ __forceinline__ void conv_lds_body(
        int id, int tid, const float* __restrict__ inter,
        const unsigned short* __restrict__ wk2, const float* __restrict__ com_b,
        float* __restrict__ om, float* smemf) {
    unsigned short* til = (unsigned short*)smemf;   // [182][24] shorts (8736B)
    int b  = id >> 7;          // 0..3
    int t7 = id & 127;
    int by = t7 >> 3;          // 0..15
    int bx = t7 & 7;           // 0..7
    int x0 = bx*16, y0 = by*8;
    int lane = tid & 63, wv = tid >> 6;
    int nn = lane & 15, qq = lane >> 4;

    // zero the dummy px row (180) once; staging never overwrites it
    if (tid < 24) til[180*24 + tid] = 0;

    // staging coords fixed per thread: cl = tid&15, cc = tid>>4 (0..15)
    int scl = tid & 15, scc = tid >> 4;
    int sgx  = x0 + scc - 1;
    int sgxc = max(sgx, 0);                 // <= 126, always in-bounds
    float sfx = ((unsigned)sgx < WW) ? 1.f : 0.f;

    f32x4 acc[2][2];
    #pragma unroll
    for (int nt = 0; nt < 2; ++nt)
        #pragma unroll
        for (int mh = 0; mh < 2; ++mh)
            #pragma unroll
            for (int j = 0; j < 4; ++j) acc[nt][mh][j] = 0.f;

    for (int cg = 0; cg < 4; ++cg) {
        __syncthreads();                    // previous cg's reads done
        const float* I = inter + ((size_t)(b*CIN + cg*16))*HW;

        // main staging: rows r=0..9, cc=0..15 (2560 elems, 10/thread)
        {
            const float* colp = I + (size_t)scl*HW + sgxc;
            unsigned short* tp = til + scc*24 + scl;
            #pragma unroll
            for (int r = 0; r < 10; ++r) {
                int gy  = y0 + r - 1;
                int gyc = min(max(gy, 0), HH-1);
                float m = ((unsigned)gy < HH) ? sfx : 0.f;
                float v = colp[(size_t)gyc*WW] * m;
                tp[r*(18*24)] = f2bf(v);
            }
        }
        // tail staging: cc=16,17 (320 elems), i = r*32 + ccb*16 + cl
        #pragma unroll
        for (int k = 0; k < 2; ++k) {
            int i = k*256 + tid;
            if (i < 320) {
                int cl  = i & 15;
                int ccb = (i >> 4) & 1;         // cc = 16+ccb
                int r   = i >> 5;               // 0..9
                int gx  = x0 + 15 + ccb;
                int gy  = y0 + r - 1;
                int gxc = min(gx, WW-1);
                int gyc = min(max(gy, 0), HH-1);
                float m = (((unsigned)gy < HH) && ((unsigned)gx < WW)) ? 1.f : 0.f;
                float v = I[(size_t)cl*HW + gyc*WW + gxc] * m;
                til[(r*18 + 16 + ccb)*24 + cl] = f2bf(v);
            }
        }
        __syncthreads();

        #pragma unroll
        for (int ch = 0; ch < 5; ++ch) {
            short8 a0 = *(const short8*)(wk2 +
                (((size_t)(cg*5 + ch)*32 + nn)*32 + qq*8));
            short8 a1 = *(const short8*)(wk2 +
                (((size_t)(cg*5 + ch)*32 + 16 + nn)*32 + qq*8));
            int tap = ch*2 + (qq >> 1);
            #pragma unroll
            for (int nt = 0; nt < 2; ++nt) {
                int row = wv*2 + nt;            // 0..7
                int px_idx;
                if (tap > 8) px_idx = 180;
                else {
                    int ky = tap/3, kx = tap%3;
                    px_idx = (row + ky)*18 + (nn + kx);
                }
                short8 bfr = *(const short8*)(til + px_idx*24 + (qq&1)*8);
                acc[nt][0] = __builtin_amdgcn_mfma_f32_16x16x32_bf16(
                                 a0, bfr, acc[nt][0], 0, 0, 0);
                acc[nt][1] = __builtin_amdgcn_mfma_f32_16x16x32_bf16(
                                 a1, bfr, acc[nt][1], 0, 0, 0);
            }
        }
    }

    float* op = om + (size_t)b*27*HW;
    #pragma unroll
    for (int nt = 0; nt < 2; ++nt) {
        int pix = (y0 + wv*2 + nt)*WW + x0 + nn;
        #pragma unroll
        for (int mh = 0; mh < 2; ++mh)
            #pragma unroll
            for (int j = 0; j < 4; ++j) {
                int oc = mh*16 + qq*4 + j;
                if (oc < 27)
                    op[(size_t)oc*HW + pix] = acc[nt][mh][j] + com_b[oc];
            }
    }
}

// ---------------------------------------------------------------------------
// K2: conv (512) + w2 (576) + fT transpose (1024) = 2112 blocks
// ---------------------------------------------------------------------------
__global__ __launch_bounds__(256) void main2_kernel(
        const float* __restrict__ input_feat,
        const float* __restrict__ inter,
        const unsigned short* __restrict__ wk2,
        const float* __restrict__ com_b,
        const float* __restrict__ weight,
        const float* __restrict__ c2w,
        const float* __restrict__ c1w,
        const float* __restrict__ fea,
        float* __restrict__ om, unsigned short* __restrict__ w2b,
        unsigned short* __restrict__ fT) {
    __shared__ __align__(16) float smem[4416];
    int id = blockIdx.x, tid = threadIdx.x;
    if (id < 512)        conv_lds_body(id, tid, inter, wk2, com_b, om, smem);
    else if (id < 1088)  w2_body(id - 512, tid, weight, c2w, c1w, fea, w2b,
                                 smem, smem + 64*65);
    else                 transpose_body(input_feat, fT, id - 1088, tid, smem);
}

// ---------------------------------------------------------------------------
// K3: main DCN GEMM, bf16 MFMA.
// v11 (resubmit after infra failure; audited — no kernel-side hang risk):
// MERGED-K + LDS GATHER TILE — the untested quadrant of the R8/R10 matrix.
// Facts: LDS-vs-global gathers = −17us in both structures (R8 53 vs R0/R5
// 70-72; R10 69 global); merged-K cut chip VALU 45% but lost by reverting
// to global gathers + fewer waves (latency-bound, not issue-bound).
// v11 composes both proven wins:
//  * 128-thread blocks (2 waves), 2048 blocks, each covering 32 px -> the
//    proven 5x36 (23KB) window still fits; 6 blocks/CU = 12 waves/CU;
//  * each wave owns a 16-px strip END-TO-END (full K=64): one bilinear/om/
//    sigmoid chain per pixel-tap (R8 computed it twice), 8 independent
//    ds_reads in flight per tap (2x R8's ILP);
//  * hi-half LDS offset = lo_offset ^ 64 (bit 6 XOR-commutes with the
//    (pl&7)<<4 swizzle mask) — 1 v_xor per corner;
//  * no loop barriers, no split-K reduce, direct C-write (R10 epilogue);
//  * pack math bit-identical to R10 (passed, absmax 0.0078125).
// __launch_bounds__(128,4) caps VGPR at 128 (est. need ~100 — meetable).
// XCD batch-binding kept (FETCH 13.6 -> 8.1 MB).
// ---------------------------------------------------------------------------
__global__ __launch_bounds__(128, 4) void dcn_main_kernel(
        const unsigned short* __restrict__ fT,
        const unsigned short* __restrict__ w2b,
        const float* __restrict__ bias2,
        const float* __restrict__ om,
        float* __restrict__ out) {
    __shared__ __align__(16) unsigned short gtile[5*36*64];   // 23040 B
    int id = blockIdx.x;                 // 0..2047
    int xcd = id & 7;                    // round-robin XCD assignment
    int jj  = id >> 3;                   // 0..255 within this XCD
    int b   = xcd >> 1;                  // 2 XCDs per batch -> per-XCD L2 fit
    int y   = jj & 127;
    int xq  = ((xcd & 1) << 1) | (jj >> 7);   // 0..3 (bijective)

    int t = threadIdx.x;                 // 0..127
    int lane = t & 63, wv = t >> 6;      // 2 waves
    int nn = lane & 15, qq = lane >> 4;
    int px0 = xq*32 + wv*16;             // wave's 16-px strip
    int x = px0 + nn;
    int pix = y*WW + x;
    const unsigned short* Fb = fT + (size_t)b*HW*64;
    const float* omb = om + (size_t)b*27*HW;
    const unsigned short* w2p = w2b + (size_t)(b*9)*4096 + qq*8;
    int co  = qq*8;                      // lo-half elem offset; hi = +32
    int cob = qq*16;                     // lo-half byte offset in 128B row

    // gather-tile window (always fully inside the image): rows [ybase,ybase+4]
    int ybase = min(max(y - 2, 0), HH - 5);        // [0,123]
    int xbase = min(max(xq*32 - 2, 0), WW - 36);   // [0,92]

    // stage 5x36 pixel rows = 1440 16B chunks, coalesced, swizzled
    char* gt = (char*)gtile;
    #pragma unroll
    for (int it = 0; it < 12; ++it) {
        int c = it*128 + t;
        if (c < 1440) {
            int pl = c >> 3;                    // local pixel 0..179
            int ci = c & 7;                     // 16B chunk in pixel
            int sy = (pl*1821) >> 16;           // pl/36 (exact for pl<216)
            int sx = pl - sy*36;
            short8 v = *(const short8*)(Fb +
                ((size_t)(ybase + sy)*WW + xbase + sx)*64 + ci*8);
            int bo = (pl*128 + ci*16) ^ ((pl & 7) << 4);
            *(short8*)(gt + bo) = v;
        }
    }

    f32x4 acc[4];
    #pragma unroll
    for (int mt = 0; mt < 4; ++mt)
        #pragma unroll
        for (int j = 0; j < 4; ++j)
            acc[mt][j] = bias2[mt*16 + qq*4 + j];

    float omy = omb[pix];
    float omx = omb[(size_t)HW + pix];
    float omm = omb[(size_t)18*HW + pix];
    __syncthreads();                             // tile ready

    #pragma unroll
    for (int p = 0; p < 9; ++p) {
        // A-frags, both K-halves (tiny, L1/L2-hot)
        short8 afrL[4], afrH[4];
        #pragma unroll
        for (int mt = 0; mt < 4; ++mt) {
            const unsigned short* ap = w2p + (size_t)p*4096 + (mt*16 + nn)*64;
            afrL[mt] = *(const short8*)(ap);
            afrH[mt] = *(const short8*)(ap + 32);
        }

        // bilinear corner weights for my pixel (computed ONCE now)
        float mv = 1.f / (1.f + expf(-omm));
        float ysv = (float)(y - 1 + p/3) + omy;
        float xsv = (float)(x - 1 + p%3) + omx;
        float y0f = floorf(ysv), x0f = floorf(xsv);
        float ly = ysv - y0f, lx = xsv - x0f;
        int y0 = (int)y0f, x0i = (int)x0f;
        int y1 = y0 + 1, x1 = x0i + 1;
        float vy0 = (y0 >= 0 && y0 < HH) ? 1.f : 0.f;
        float vy1 = (y1 >= 0 && y1 < HH) ? 1.f : 0.f;
        float vx0 = (x0i >= 0 && x0i < WW) ? 1.f : 0.f;
        float vx1 = (x1 >= 0 && x1 < WW) ? 1.f : 0.f;
        float w00 = (1.f-ly)*(1.f-lx)*mv * vy0*vx0;
        float w01 = (1.f-ly)*lx      *mv * vy0*vx1;
        float w10 = ly      *(1.f-lx)*mv * vy1*vx0;
        float w11 = ly      *lx      *mv * vy1*vx1;
        int y0c = min(max(y0,0),HH-1), y1c = min(max(y1,0),HH-1);
        int x0c = min(max(x0i,0),WW-1), x1c = min(max(x1,0),WW-1);

        // prefetch next p's om
        if (p < 8) {
            omy = omb[(size_t)(2*p+2)*HW + pix];
            omx = omb[(size_t)(2*p+3)*HW + pix];
            omm = omb[(size_t)(19+p )*HW + pix];
        }

        // gather 4 corners x 2 K-halves: LDS fast path, global fallback
        short8 c00L, c01L, c10L, c11L, c00H, c01H, c10H, c11H;
        {
            int sy0 = y0c - ybase, sy1 = y1c - ybase;
            int sx0 = x0c - xbase, sx1 = x1c - xbase;
            bool allin = ((unsigned)sy0 < 5) & ((unsigned)sy1 < 5) &
                         ((unsigned)sx0 < 36) & ((unsigned)sx1 < 36);
            if (allin) {
                int p00 = sy0*36 + sx0, p01 = sy0*36 + sx1;
                int p10 = sy1*36 + sx0, p11 = sy1*36 + sx1;
                int o00 = (p00*128 + cob) ^ ((p00&7)<<4);
                int o01 = (p01*128 + cob) ^ ((p01&7)<<4);
                int o10 = (p10*128 + cob) ^ ((p10&7)<<4);
                int o11 = (p11*128 + cob) ^ ((p11&7)<<4);
                c00L = *(const short8*)(gt + o00);
                c01L = *(const short8*)(gt + o01);
                c10L = *(const short8*)(gt + o10);
                c11L = *(const short8*)(gt + o11);
                c00H = *(const short8*)(gt + (o00 ^ 64));
                c01H = *(const short8*)(gt + (o01 ^ 64));
                c10H = *(const short8*)(gt + (o10 ^ 64));
                c11H = *(const short8*)(gt + (o11 ^ 64));
            } else {
                int i00 = y0c*WW + x0c, i01 = y0c*WW + x1c;
                int i10 = y1c*WW + x0c, i11 = y1c*WW + x1c;
                const unsigned short* g00 = Fb + (size_t)i00*64 + co;
                const unsigned short* g01 = Fb + (size_t)i01*64 + co;
                const unsigned short* g10 = Fb + (size_t)i10*64 + co;
                const unsigned short* g11 = Fb + (size_t)i11*64 + co;
                c00L = *(const short8*)(g00);
                c01L = *(const short8*)(g01);
                c10L = *(const short8*)(g10);
                c11L = *(const short8*)(g11);
                c00H = *(const short8*)(g00 + 32);
                c01H = *(const short8*)(g01 + 32);
                c10H = *(const short8*)(g10 + 32);
                c11H = *(const short8*)(g11 + 32);
            }
        }

        // pack lo half: f32x2 weighted sum + v_cvt_pk_bf16_f32
        uint4v u00 = __builtin_bit_cast(uint4v, c00L);
        uint4v u01 = __builtin_bit_cast(uint4v, c01L);
        uint4v u10 = __builtin_bit_cast(uint4v, c10L);
        uint4v u11 = __builtin_bit_cast(uint4v, c11L);
        unsigned int pw[4];
        #pragma unroll
        for (int jp = 0; jp < 4; ++jp) {
            f32x2 A = bfpair(u00[jp]);
            f32x2 B = bfpair(u01[jp]);
            f32x2 C = bfpair(u10[jp]);
            f32x2 D = bfpair(u11[jp]);
            f32x2 r = A*w00 + B*w01 + C*w10 + D*w11;
            pw[jp] = cvtpk_bf16(r[0], r[1]);
        }
        uint4v u4L = {pw[0], pw[1], pw[2], pw[3]};
        short8 bfrL = __builtin_bit_cast(short8, u4L);
        #pragma unroll
        for (int mt = 0; mt < 4; ++mt)
            acc[mt] = __builtin_amdgcn_mfma_f32_16x16x32_bf16(
                          afrL[mt], bfrL, acc[mt], 0, 0, 0);

        // pack hi half
        u00 = __builtin_bit_cast(uint4v, c00H);
        u01 = __builtin_bit_cast(uint4v, c01H);
        u10 = __builtin_bit_cast(uint4v, c10H);
        u11 = __builtin_bit_cast(uint4v, c11H);
        #pragma unroll
        for (int jp = 0; jp < 4; ++jp) {
            f32x2 A = bfpair(u00[jp]);
            f32x2 B = bfpair(u01[jp]);
            f32x2 C = bfpair(u10[jp]);
            f32x2 D = bfpair(u11[jp]);
            f32x2 r = A*w00 + B*w01 + C*w10 + D*w11;
            pw[jp] = cvtpk_bf16(r[0], r[1]);
        }
        uint4v u4H = {pw[0], pw[1], pw[2], pw[3]};
        short8 bfrH = __builtin_bit_cast(short8, u4H);
        #pragma unroll
        for (int mt = 0; mt < 4; ++mt)
            acc[mt] = __builtin_amdgcn_mfma_f32_16x16x32_bf16(
                          afrH[mt], bfrH, acc[mt], 0, 0, 0);
    }

    // direct write — no split-K partner, no barrier
    float* outp = out + (size_t)b*COUT*HW + (size_t)y*WW + px0 + nn;
    #pragma unroll
    for (int mt = 0; mt < 4; ++mt)
        #pragma unroll
        for (int j = 0; j < 4; ++j)
            outp[(size_t)(mt*16 + qq*4 + j)*HW] = acc[mt][j];
}

// ---------------------------------------------------------------------------
extern "C" void kernel_launch(void* const* d_in, const int* in_sizes, int n_in,
                              void* d_out, int out_size, void* d_ws, size_t ws_size,
                              hipStream_t stream) {
    const float* input_feat = (const float*)d_in[0];
    const float* inter      = (const float*)d_in[1];
    const float* fea        = (const float*)d_in[2];
    const float* weight     = (const float*)d_in[3];
    const float* bias       = (const float*)d_in[4];
    const float* com_w      = (const float*)d_in[5];
    const float* com_b      = (const float*)d_in[6];
    const float* c1w        = (const float*)d_in[7];
    const float* c2w        = (const float*)d_in[8];
    float* out = (float*)d_out;

    float* ws    = (float*)d_ws;
    float* bias2 = ws + 256;                               // 64 (in pad area)
    unsigned short* w2b = (unsigned short*)(ws + 512);     // 147456 us
    float* om    = ws + 512 + 73728;                       // 1769472 f
    unsigned short* wk2 = (unsigned short*)(om + 1769472); // 20480 us
    unsigned short* fT  = wk2 + 20480;                     // 4194304 us

    prep_kernel<<<81, 256, 0, stream>>>(com_w, c2w, bias, wk2, bias2);
    main2_kernel<<<2112, 256, 0, stream>>>(input_feat, inter, wk2, com_b,
                                           weight, c2w, c1w, fea, om, w2b, fT);
    dcn_main_kernel<<<2048, 128, 0, stream>>>(fT, w2b, bias2, om, out);
}

// Round 13
// 160.813 us; speedup vs baseline: 1.1054x; 1.0164x over previous
//
#include <hip/hip_runtime.h>
#include <math.h>

// Problem constants
#define BB 4
#define CIN 64
#define COUT 64
#define HH 128
#define WW 128
#define HW (HH*WW)

typedef __attribute__((ext_vector_type(8))) short short8;   // 8 bf16 = 4 VGPRs
typedef __attribute__((ext_vector_type(4))) float f32x4;
typedef __attribute__((ext_vector_type(2))) float f32x2;
typedef __attribute__((ext_vector_type(4))) unsigned int uint4v;

static __device__ __forceinline__ unsigned short f2bf(float f) {
    unsigned int u = __builtin_bit_cast(unsigned int, f);
    u += 0x7fffu + ((u >> 16) & 1u);          // round-to-nearest-even
    return (unsigned short)(u >> 16);
}
static __device__ __forceinline__ float bf2f(unsigned short h) {
    unsigned int u = ((unsigned int)h) << 16;
    return __builtin_bit_cast(float, u);
}
// pack 2 f32 -> 2 bf16 in one HW instruction (RNE, == f2bf on finite vals)
static __device__ __forceinline__ unsigned int cvtpk_bf16(float lo, float hi) {
    unsigned int r;
    asm("v_cvt_pk_bf16_f32 %0, %1, %2" : "=v"(r) : "v"(lo), "v"(hi));
    return r;
}
// unpack 2 bf16 from a u32 into float2 (2 inst)
static __device__ __forceinline__ f32x2 bfpair(unsigned int u) {
    f32x2 r;
    r[0] = __builtin_bit_cast(float, u << 16);
    r[1] = __builtin_bit_cast(float, u & 0xffff0000u);
    return r;
}

// ---------------------------------------------------------------------------
// K1: wkpack (80 blocks) + bias2 (1 block).  Tiny; everything else moved out.
// ---------------------------------------------------------------------------
__global__ __launch_bounds__(256) void prep_kernel(
        const float* __restrict__ com_w, const float* __restrict__ c2w,
        const float* __restrict__ bias,
        unsigned short* __restrict__ wk2, float* __restrict__ bias2) {
    int id = blockIdx.x, tid = threadIdx.x;
    if (id < 80) {
        int i = id*256 + tid;               // < 20480
        int k = i & 31, oc = (i >> 5) & 31;
        int cc5 = i >> 10;                  // cg*5 + chunk
        int cg = cc5 / 5, ch = cc5 % 5;
        int tap = ch*2 + (k >> 4);
        int c = cg*16 + (k & 15);
        float v = 0.f;
        if (tap < 9 && oc < 27) v = com_w[((size_t)oc*64 + c)*9 + tap];
        wk2[i] = f2bf(v);
    } else if (tid < COUT) {
        float s2 = 0.f;
        for (int o = 0; o < COUT; ++o) s2 += c2w[tid*COUT + o] * bias[o];
        bias2[tid] = s2;
    }
}

// ---------------------------------------------------------------------------
// channel-last bf16 transpose of one (b, 64-px strip): src[b][c][px]->dst[b][px][c]
// v13: float4 global loads (4 iters/thread instead of 16 scalar — G13).
// Same values loaded, same f2bf converts: numerics identical.
// ---------------------------------------------------------------------------
static __device__ __forceinline__ void transpose_body(
        const float* __restrict__ srcb, unsigned short* __restrict__ dstb,
        int tb, int tid, float* lt /* 64*65 floats */) {
    int b = tb >> 8;
    int px0 = (tb & 255) * 64;
    const float* src = srcb + (size_t)b*CIN*HW + px0;
    #pragma unroll
    for (int it = 0; it < 4; ++it) {
        int i = it*256 + tid;               // 0..1023
        int c = i >> 4, px4 = (i & 15) * 4; // 16B-aligned (px0 mult of 64)
        f32x4 v = *(const f32x4*)(src + (size_t)c*HW + px4);
        lt[c*65 + px4 + 0] = v[0];
        lt[c*65 + px4 + 1] = v[1];
        lt[c*65 + px4 + 2] = v[2];
        lt[c*65 + px4 + 3] = v[3];
    }
    __syncthreads();
    int q = tid & 3, px = tid >> 2;
    unsigned short* dst = dstb + ((size_t)b*HW + px0 + px)*64 + q*16;
    #pragma unroll
    for (int s = 0; s < 2; ++s) {
        short8 pk;
        #pragma unroll
        for (int j = 0; j < 8; ++j)
            pk[j] = (short)f2bf(lt[(q*16 + s*8 + j)*65 + px]);
        *(short8*)(dst + s*8) = pk;
    }
}

// ---------------------------------------------------------------------------
// w2 with INLINE fvec (wave-reduced): W2b[b][p][o2][c] bf16 (MFMA A layout)
// Unswizzled: dcn reads A-frags directly from global (L1/L2-hot).
// ---------------------------------------------------------------------------
static __device__ __forceinline__ void w2_body(
        int wid, int tid, const float* __restrict__ weight,
        const float* __restrict__ c2w, const float* __restrict__ c1w,
        const float* __restrict__ fea,
        unsigned short* __restrict__ w2b, float* c2s, float* wcol) {
    int o2 = tid & 63, ci = tid >> 6;
    int lane = tid & 63;
    int bp = wid >> 4;
    int c_base = (wid & 15)*4;
    int p = bp % 9, b = bp / 9;
    int c = c_base + ci;

    // inline fvec[b][c] for this wave's c: 4 MAC/lane + wave reduce
    float part = 0.f;
    #pragma unroll
    for (int s = 0; s < 4; ++s)
        part += c1w[c*(4*CIN) + lane + s*64] * fea[b*(4*CIN) + lane + s*64];
    #pragma unroll
    for (int off = 32; off; off >>= 1) part += __shfl_down(part, off);
    float fv = __shfl(part, 0);

    for (int idx = tid; idx < 4096; idx += 256) {
        int o2r = idx >> 6, oc = idx & 63;
        c2s[oc*65 + o2r] = c2w[idx];
    }
    {
        int o = tid & 63, cw = tid >> 6;
        wcol[cw*64 + o] = weight[(o*CIN + (c_base + cw))*9 + p];
    }
    __syncthreads();
    float s = 0.f;
    #pragma unroll 8
    for (int o = 0; o < COUT; ++o) s += c2s[o*65 + o2] * wcol[ci*64 + o];
    w2b[(size_t)bp*4096 + o2*64 + c] = f2bf(s * fv);
}

// ---------------------------------------------------------------------------
// conv v2 (round-4-proven): 512 blocks = b(4) x by(16) x bx(8); tile = 8 rows
// x 16 px, ALL 27 output channels per block (B-tile staged ONCE, each ds_read
// feeds 2 MFMAs).  Division-free branch-free staging.
// ---------------------------------------------------------------------------
static __device__ __forceinline__ void conv_lds_body(
        int id, int tid, const float* __restrict__ inter,
        const unsigned short* __restrict__ wk2, const float* __restrict__ com_b,
        float* __restrict__ om, float* smemf) {
    unsigned short* til = (unsigned short*)smemf;   // [182][24] shorts (8736B)
    int b  = id >> 7;          // 0..3
    int t7 = id & 127;
    int by = t7 >> 3;          // 0..15
    int bx = t7 & 7;           // 0..7
    int x0 = bx*16, y0 = by*8;
    int lane = tid & 63, wv = tid >> 6;
    int nn = lane & 15, qq = lane >> 4;

    // zero the dummy px row (180) once; staging never overwrites it
    if (tid < 24) til[180*24 + tid] = 0;

    // staging coords fixed per thread: cl = tid&15, cc = tid>>4 (0..15)
    int scl = tid & 15, scc = tid >> 4;
    int sgx  = x0 + scc - 1;
    int sgxc = max(sgx, 0);                 // <= 126, always in-bounds
    float sfx = ((unsigned)sgx < WW) ? 1.f : 0.f;

    f32x4 acc[2][2];
    #pragma unroll
    for (int nt = 0; nt < 2; ++nt)
        #pragma unroll
        for (int mh = 0; mh < 2; ++mh)
            #pragma unroll
            for (int j = 0; j < 4; ++j) acc[nt][mh][j] = 0.f;

    for (int cg = 0; cg < 4; ++cg) {
        __syncthreads();                    // previous cg's reads done
        const float* I = inter + ((size_t)(b*CIN + cg*16))*HW;

        // main staging: rows r=0..9, cc=0..15 (2560 elems, 10/thread)
        {
            const float* colp = I + (size_t)scl*HW + sgxc;
            unsigned short* tp = til + scc*24 + scl;
            #pragma unroll
            for (int r = 0; r < 10; ++r) {
                int gy  = y0 + r - 1;
                int gyc = min(max(gy, 0), HH-1);
                float m = ((unsigned)gy < HH) ? sfx : 0.f;
                float v = colp[(size_t)gyc*WW] * m;
                tp[r*(18*24)] = f2bf(v);
            }
        }
        // tail staging: cc=16,17 (320 elems), i = r*32 + ccb*16 + cl
        #pragma unroll
        for (int k = 0; k < 2; ++k) {
            int i = k*256 + tid;
            if (i < 320) {
                int cl  = i & 15;
                int ccb = (i >> 4) & 1;         // cc = 16+ccb
                int r   = i >> 5;               // 0..9
                int gx  = x0 + 15 + ccb;
                int gy  = y0 + r - 1;
                int gxc = min(gx, WW-1);
                int gyc = min(max(gy, 0), HH-1);
                float m = (((unsigned)gy < HH) && ((unsigned)gx < WW)) ? 1.f : 0.f;
                float v = I[(size_t)cl*HW + gyc*WW + gxc] * m;
                til[(r*18 + 16 + ccb)*24 + cl] = f2bf(v);
            }
        }
        __syncthreads();

        #pragma unroll
        for (int ch = 0; ch < 5; ++ch) {
            short8 a0 = *(const short8*)(wk2 +
                (((size_t)(cg*5 + ch)*32 + nn)*32 + qq*8));
            short8 a1 = *(const short8*)(wk2 +
                (((size_t)(cg*5 + ch)*32 + 16 + nn)*32 + qq*8));
            int tap = ch*2 + (qq >> 1);
            #pragma unroll
            for (int nt = 0; nt < 2; ++nt) {
                int row = wv*2 + nt;            // 0..7
                int px_idx;
                if (tap > 8) px_idx = 180;
                else {
                    int ky = tap/3, kx = tap%3;
                    px_idx = (row + ky)*18 + (nn + kx);
                }
                short8 bfr = *(const short8*)(til + px_idx*24 + (qq&1)*8);
                acc[nt][0] = __builtin_amdgcn_mfma_f32_16x16x32_bf16(
                                 a0, bfr, acc[nt][0], 0, 0, 0);
                acc[nt][1] = __builtin_amdgcn_mfma_f32_16x16x32_bf16(
                                 a1, bfr, acc[nt][1], 0, 0, 0);
            }
        }
    }

    float* op = om + (size_t)b*27*HW;
    #pragma unroll
    for (int nt = 0; nt < 2; ++nt) {
        int pix = (y0 + wv*2 + nt)*WW + x0 + nn;
        #pragma unroll
        for (int mh = 0; mh < 2; ++mh)
            #pragma unroll
            for (int j = 0; j < 4; ++j) {
                int oc = mh*16 + qq*4 + j;
                if (oc < 27)
                    op[(size_t)oc*HW + pix] = acc[nt][mh][j] + com_b[oc];
            }
    }
}

// ---------------------------------------------------------------------------
// K2: conv (512) + w2 (576) + fT transpose (1024) = 2112 blocks
// ---------------------------------------------------------------------------
__global__ __launch_bounds__(256) void main2_kernel(
        const float* __restrict__ input_feat,
        const float* __restrict__ inter,
        const unsigned short* __restrict__ wk2,
        const float* __restrict__ com_b,
        const float* __restrict__ weight,
        const float* __restrict__ c2w,
        const float* __restrict__ c1w,
        const float* __restrict__ fea,
        float* __restrict__ om, unsigned short* __restrict__ w2b,
        unsigned short* __restrict__ fT) {
    __shared__ __align__(16) float smem[4416];
    int id = blockIdx.x, tid = threadIdx.x;
    if (id < 512)        conv_lds_body(id, tid, inter, wk2, com_b, om, smem);
    else if (id < 1088)  w2_body(id - 512, tid, weight, c2w, c1w, fea, w2b,
                                 smem, smem + 64*65);
    else                 transpose_body(input_feat, fT, id - 1088, tid, smem);
}

// ---------------------------------------------------------------------------
// K3: main DCN GEMM, bf16 MFMA, split-K across wave pairs.
// v13 = byte-exact revert to the R8 kernel (proven 53.0 us, best of 12
// rounds).  The completed structure matrix (split/merged-K x LDS/global
// gathers, plus pack-vec, LDS-shrink, launch-bounds, barrier variants) shows
// this is the local optimum: split-K's duplicated scalar work fills the
// gather-latency shadow, so removing it never pays.
//  * XCD batch-binding (FETCH 13.6 -> 8.1 MB), 5-row swizzled LDS gather
//    window + global fallback, barrier-free loop, pk_fma +
//    v_cvt_pk_bf16_f32 pack, split-K reduce epilogue.
// ---------------------------------------------------------------------------
__global__ __launch_bounds__(256) void dcn_main_kernel(
        const unsigned short* __restrict__ fT,
        const unsigned short* __restrict__ w2b,
        const float* __restrict__ bias2,
        const float* __restrict__ om,
        float* __restrict__ out) {
    __shared__ __align__(16) unsigned short gtile[5*36*64];   // 23040 B
    int id = blockIdx.x;                 // 0..2047
    int xcd = id & 7;                    // round-robin XCD assignment
    int jj  = id >> 3;                   // 0..255 within this XCD
    int b   = xcd >> 1;                  // 2 XCDs per batch -> per-XCD L2 fit
    int y   = jj & 127;
    int xq  = ((xcd & 1) << 1) | (jj >> 7);   // 0..3 (bijective)

    int t = threadIdx.x;
    int lane = t & 63, wv = t >> 6;
    int strip = wv >> 1, kh = wv & 1;
    int nn = lane & 15, qq = lane >> 4;
    int px0 = xq*32 + strip*16;
    int x = px0 + nn;
    int pix = y*WW + x;
    const unsigned short* Fb = fT + (size_t)b*HW*64;
    const float* omb = om + (size_t)b*27*HW;
    const unsigned short* w2p = w2b + (size_t)(b*9)*4096 + kh*32 + qq*8;
    int co  = kh*32 + qq*8;       // element offset in a 64-ch pixel row
    int cob = kh*64 + qq*16;      // byte offset within a 128B pixel row

    // gather-tile window (always fully inside the image): rows [ybase,ybase+4]
    int ybase = min(max(y - 2, 0), HH - 5);        // [0,123]
    int xbase = min(max(xq*32 - 2, 0), WW - 36);   // [0,92]

    // stage 5x36 pixel rows = 1440 16B chunks, coalesced, swizzled
    char* gt = (char*)gtile;
    #pragma unroll
    for (int it = 0; it < 6; ++it) {
        int c = it*256 + t;
        if (c < 1440) {
            int pl = c >> 3;                    // local pixel 0..179
            int ci = c & 7;                     // 16B chunk in pixel
            int sy = (pl*1821) >> 16;           // pl/36 (exact for pl<216)
            int sx = pl - sy*36;
            short8 v = *(const short8*)(Fb +
                ((size_t)(ybase + sy)*WW + xbase + sx)*64 + ci*8);
            int bo = (pl*128 + ci*16) ^ ((pl & 7) << 4);
            *(short8*)(gt + bo) = v;
        }
    }

    f32x4 acc[4];
    #pragma unroll
    for (int mt = 0; mt < 4; ++mt)
        #pragma unroll
        for (int j = 0; j < 4; ++j)
            acc[mt][j] = kh ? bias2[mt*16 + qq*4 + j] : 0.f;

    float omy = omb[pix];
    float omx = omb[(size_t)HW + pix];
    float omm = omb[(size_t)18*HW + pix];
    __syncthreads();                             // tile ready

    #pragma unroll
    for (int p = 0; p < 9; ++p) {
        // A-frags for my K-half (tiny, L1/L2-hot)
        short8 afr[4];
        #pragma unroll
        for (int mt = 0; mt < 4; ++mt)
            afr[mt] = *(const short8*)(w2p + (size_t)p*4096 + (mt*16 + nn)*64);

        // bilinear corner weights for my pixel
        float mv = 1.f / (1.f + expf(-omm));
        float ysv = (float)(y - 1 + p/3) + omy;
        float xsv = (float)(x - 1 + p%3) + omx;
        float y0f = floorf(ysv), x0f = floorf(xsv);
        float ly = ysv - y0f, lx = xsv - x0f;
        int y0 = (int)y0f, x0i = (int)x0f;
        int y1 = y0 + 1, x1 = x0i + 1;
        float vy0 = (y0 >= 0 && y0 < HH) ? 1.f : 0.f;
        float vy1 = (y1 >= 0 && y1 < HH) ? 1.f : 0.f;
        float vx0 = (x0i >= 0 && x0i < WW) ? 1.f : 0.f;
        float vx1 = (x1 >= 0 && x1 < WW) ? 1.f : 0.f;
        float w00 = (1.f-ly)*(1.f-lx)*mv * vy0*vx0;
        float w01 = (1.f-ly)*lx      *mv * vy0*vx1;
        float w10 = ly      *(1.f-lx)*mv * vy1*vx0;
        float w11 = ly      *lx      *mv * vy1*vx1;
        int y0c = min(max(y0,0),HH-1), y1c = min(max(y1,0),HH-1);
        int x0c = min(max(x0i,0),WW-1), x1c = min(max(x1,0),WW-1);

        // prefetch next p's om
        if (p < 8) {
            omy = omb[(size_t)(2*p+2)*HW + pix];
            omx = omb[(size_t)(2*p+3)*HW + pix];
            omm = omb[(size_t)(19+p )*HW + pix];
        }

        // gather 4 corners: LDS fast path, global fallback (rare)
        short8 c00, c01, c10, c11;
        {
            int sy0 = y0c - ybase, sy1 = y1c - ybase;
            int sx0 = x0c - xbase, sx1 = x1c - xbase;
            bool allin = ((unsigned)sy0 < 5) & ((unsigned)sy1 < 5) &
                         ((unsigned)sx0 < 36) & ((unsigned)sx1 < 36);
            if (allin) {
                int p00 = sy0*36 + sx0, p01 = sy0*36 + sx1;
                int p10 = sy1*36 + sx0, p11 = sy1*36 + sx1;
                c00 = *(const short8*)(gt + ((p00*128 + cob) ^ ((p00&7)<<4)));
                c01 = *(const short8*)(gt + ((p01*128 + cob) ^ ((p01&7)<<4)));
                c10 = *(const short8*)(gt + ((p10*128 + cob) ^ ((p10&7)<<4)));
                c11 = *(const short8*)(gt + ((p11*128 + cob) ^ ((p11&7)<<4)));
            } else {
                int i00 = y0c*WW + x0c, i01 = y0c*WW + x1c;
                int i10 = y1c*WW + x0c, i11 = y1c*WW + x1c;
                c00 = *(const short8*)(Fb + (size_t)i00*64 + co);
                c01 = *(const short8*)(Fb + (size_t)i01*64 + co);
                c10 = *(const short8*)(Fb + (size_t)i10*64 + co);
                c11 = *(const short8*)(Fb + (size_t)i11*64 + co);
            }
        }

        // pack: float2 weighted sum (v_pk_fma_f32) + v_cvt_pk_bf16_f32
        uint4v u00 = __builtin_bit_cast(uint4v, c00);
        uint4v u01 = __builtin_bit_cast(uint4v, c01);
        uint4v u10 = __builtin_bit_cast(uint4v, c10);
        uint4v u11 = __builtin_bit_cast(uint4v, c11);
        unsigned int pw[4];
        #pragma unroll
        for (int jp = 0; jp < 4; ++jp) {
            f32x2 A = bfpair(u00[jp]);
            f32x2 B = bfpair(u01[jp]);
            f32x2 C = bfpair(u10[jp]);
            f32x2 D = bfpair(u11[jp]);
            f32x2 r = A*w00 + B*w01 + C*w10 + D*w11;
            pw[jp] = cvtpk_bf16(r[0], r[1]);
        }
        uint4v u4 = {pw[0], pw[1], pw[2], pw[3]};
        short8 bfr = __builtin_bit_cast(short8, u4);

        // MFMA (my K-half only)
        #pragma unroll
        for (int mt = 0; mt < 4; ++mt)
            acc[mt] = __builtin_amdgcn_mfma_f32_16x16x32_bf16(
                          afr[mt], bfr, acc[mt], 0, 0, 0);
    }

    // combine wave-pair partials; reduction buffer ALIASES gtile, so first
    // ensure all waves finished their LDS gathers.
    __syncthreads();
    float* red = (float*)gtile;
    if (kh == 0) {
        #pragma unroll
        for (int mt = 0; mt < 4; ++mt)
            #pragma unroll
            for (int j = 0; j < 4; ++j)
                red[(mt*4 + j)*128 + strip*64 + lane] = acc[mt][j];
    }
    __syncthreads();
    if (kh == 1) {
        float* outp = out + (size_t)b*COUT*HW + (size_t)y*WW + px0 + nn;
        #pragma unroll
        for (int mt = 0; mt < 4; ++mt)
            #pragma unroll
            for (int j = 0; j < 4; ++j)
                outp[(size_t)(mt*16 + qq*4 + j)*HW] =
                    acc[mt][j] + red[(mt*4 + j)*128 + strip*64 + lane];
    }
}

// ---------------------------------------------------------------------------
extern "C" void kernel_launch(void* const* d_in, const int* in_sizes, int n_in,
                              void* d_out, int out_size, void* d_ws, size_t ws_size,
                              hipStream_t stream) {
    const float* input_feat = (const float*)d_in[0];
    const float* inter      = (const float*)d_in[1];
    const float* fea        = (const float*)d_in[2];
    const float* weight     = (const float*)d_in[3];
    const float* bias       = (const float*)d_in[4];
    const float* com_w      = (const float*)d_in[5];
    const float* com_b      = (const float*)d_in[6];
    const float* c1w        = (const float*)d_in[7];
    const float* c2w        = (const float*)d_in[8];
    float* out = (float*)d_out;

    float* ws    = (float*)d_ws;
    float* bias2 = ws + 256;                               // 64 (in pad area)
    unsigned short* w2b = (unsigned short*)(ws + 512);     // 147456 us
    float* om    = ws + 512 + 73728;                       // 1769472 f
    unsigned short* wk2 = (unsigned short*)(om + 1769472); // 20480 us
    unsigned short* fT  = wk2 + 20480;                     // 4194304 us

    prep_kernel<<<81, 256, 0, stream>>>(com_w, c2w, bias, wk2, bias2);
    main2_kernel<<<2112, 256, 0, stream>>>(input_feat, inter, wk2, com_b,
                                           weight, c2w, c1w, fea, om, w2b, fT);
    dcn_main_kernel<<<2048, 256, 0, stream>>>(fT, w2b, bias2, om, out);
}

// Round 14
// 156.011 us; speedup vs baseline: 1.1395x; 1.0308x over previous
//
#include <hip/hip_runtime.h>
#include <math.h>

// Problem constants
#define BB 4
#define CIN 64
#define COUT 64
#define HH 128
#define WW 128
#define HW (HH*WW)

typedef __attribute__((ext_vector_type(8))) short short8;   // 8 bf16 = 4 VGPRs
typedef __attribute__((ext_vector_type(4))) float f32x4;
typedef __attribute__((ext_vector_type(2))) float f32x2;
typedef __attribute__((ext_vector_type(4))) unsigned int uint4v;

static __device__ __forceinline__ unsigned short f2bf(float f) {
    unsigned int u = __builtin_bit_cast(unsigned int, f);
    u += 0x7fffu + ((u >> 16) & 1u);          // round-to-nearest-even
    return (unsigned short)(u >> 16);
}
static __device__ __forceinline__ float bf2f(unsigned short h) {
    unsigned int u = ((unsigned int)h) << 16;
    return __builtin_bit_cast(float, u);
}
// pack 2 f32 -> 2 bf16 in one HW instruction (RNE, == f2bf on finite vals)
static __device__ __forceinline__ unsigned int cvtpk_bf16(float lo, float hi) {
    unsigned int r;
    asm("v_cvt_pk_bf16_f32 %0, %1, %2" : "=v"(r) : "v"(lo), "v"(hi));
    return r;
}
// unpack 2 bf16 from a u32 into float2 (2 inst)
static __device__ __forceinline__ f32x2 bfpair(unsigned int u) {
    f32x2 r;
    r[0] = __builtin_bit_cast(float, u << 16);
    r[1] = __builtin_bit_cast(float, u & 0xffff0000u);
    return r;
}

// ---------------------------------------------------------------------------
// K1: wkpack (80 blocks) + bias2 (1 block).  Tiny; everything else moved out.
// ---------------------------------------------------------------------------
__global__ __launch_bounds__(256) void prep_kernel(
        const float* __restrict__ com_w, const float* __restrict__ c2w,
        const float* __restrict__ bias,
        unsigned short* __restrict__ wk2, float* __restrict__ bias2) {
    int id = blockIdx.x, tid = threadIdx.x;
    if (id < 80) {
        int i = id*256 + tid;               // < 20480
        int k = i & 31, oc = (i >> 5) & 31;
        int cc5 = i >> 10;                  // cg*5 + chunk
        int cg = cc5 / 5, ch = cc5 % 5;
        int tap = ch*2 + (k >> 4);
        int c = cg*16 + (k & 15);
        float v = 0.f;
        if (tap < 9 && oc < 27) v = com_w[((size_t)oc*64 + c)*9 + tap];
        wk2[i] = f2bf(v);
    } else if (tid < COUT) {
        float s2 = 0.f;
        for (int o = 0; o < COUT; ++o) s2 += c2w[tid*COUT + o] * bias[o];
        bias2[tid] = s2;
    }
}

// ---------------------------------------------------------------------------
// channel-last bf16 transpose of one (b, 64-px strip): src[b][c][px]->dst[b][px][c]
// float4 global loads (4 iters/thread — G13).  Numerics identical.
// ---------------------------------------------------------------------------
static __device__ __forceinline__ void transpose_body(
        const float* __restrict__ srcb, unsigned short* __restrict__ dstb,
        int tb, int tid, float* lt /* 64*65 floats */) {
    int b = tb >> 8;
    int px0 = (tb & 255) * 64;
    const float* src = srcb + (size_t)b*CIN*HW + px0;
    #pragma unroll
    for (int it = 0; it < 4; ++it) {
        int i = it*256 + tid;               // 0..1023
        int c = i >> 4, px4 = (i & 15) * 4; // 16B-aligned (px0 mult of 64)
        f32x4 v = *(const f32x4*)(src + (size_t)c*HW + px4);
        lt[c*65 + px4 + 0] = v[0];
        lt[c*65 + px4 + 1] = v[1];
        lt[c*65 + px4 + 2] = v[2];
        lt[c*65 + px4 + 3] = v[3];
    }
    __syncthreads();
    int q = tid & 3, px = tid >> 2;
    unsigned short* dst = dstb + ((size_t)b*HW + px0 + px)*64 + q*16;
    #pragma unroll
    for (int s = 0; s < 2; ++s) {
        short8 pk;
        #pragma unroll
        for (int j = 0; j < 8; ++j)
            pk[j] = (short)f2bf(lt[(q*16 + s*8 + j)*65 + px]);
        *(short8*)(dst + s*8) = pk;
    }
}

// ---------------------------------------------------------------------------
// w2 with INLINE fvec (wave-reduced): W2b[b][p][o2][c] bf16 (MFMA A layout)
// Unswizzled: dcn reads A-frags directly from global (L1/L2-hot).
// ---------------------------------------------------------------------------
static __device__ __forceinline__ void w2_body(
        int wid, int tid, const float* __restrict__ weight,
        const float* __restrict__ c2w, const float* __restrict__ c1w,
        const float* __restrict__ fea,
        unsigned short* __restrict__ w2b, float* c2s, float* wcol) {
    int o2 = tid & 63, ci = tid >> 6;
    int lane = tid & 63;
    int bp = wid >> 4;
    int c_base = (wid & 15)*4;
    int p = bp % 9, b = bp / 9;
    int c = c_base + ci;

    // inline fvec[b][c] for this wave's c: 4 MAC/lane + wave reduce
    float part = 0.f;
    #pragma unroll
    for (int s = 0; s < 4; ++s)
        part += c1w[c*(4*CIN) + lane + s*64] * fea[b*(4*CIN) + lane + s*64];
    #pragma unroll
    for (int off = 32; off; off >>= 1) part += __shfl_down(part, off);
    float fv = __shfl(part, 0);

    for (int idx = tid; idx < 4096; idx += 256) {
        int o2r = idx >> 6, oc = idx & 63;
        c2s[oc*65 + o2r] = c2w[idx];
    }
    {
        int o = tid & 63, cw = tid >> 6;
        wcol[cw*64 + o] = weight[(o*CIN + (c_base + cw))*9 + p];
    }
    __syncthreads();
    float s = 0.f;
    #pragma unroll 8
    for (int o = 0; o < COUT; ++o) s += c2s[o*65 + o2] * wcol[ci*64 + o];
    w2b[(size_t)bp*4096 + o2*64 + c] = f2bf(s * fv);
}

// ---------------------------------------------------------------------------
// conv v3: 512 blocks = b(4) x by(16) x bx(8); tile = 8 rows x 16 px, ALL 27
// output channels per block.  v14 change: staging thread mapping swapped to
// x-FASTEST (scl = tid>>4 channel, scc = tid&15 x-offset) -> lanes 0..15 read
// 16 CONTIGUOUS floats of one channel row: 4 memory transactions per wave
// load instead of 16 (was channel-fastest: 16 lanes -> 16 planes 64KB apart).
// LDS write goes ~2-way -> ~2-4-way bank aliasing (<=1.58x on a store) — a
// good trade.  Same (scl,scc) coverage, same destinations: numerics identical.
// ---------------------------------------------------------------------------
static __device__ __forceinline__ void conv_lds_body(
        int id, int tid, const float* __restrict__ inter,
        const unsigned short* __restrict__ wk2, const float* __restrict__ com_b,
        float* __restrict__ om, float* smemf) {
    unsigned short* til = (unsigned short*)smemf;   // [182][24] shorts (8736B)
    int b  = id >> 7;          // 0..3
    int t7 = id & 127;
    int by = t7 >> 3;          // 0..15
    int bx = t7 & 7;           // 0..7
    int x0 = bx*16, y0 = by*8;
    int lane = tid & 63, wv = tid >> 6;
    int nn = lane & 15, qq = lane >> 4;

    // zero the dummy px row (180) once; staging never overwrites it
    if (tid < 24) til[180*24 + tid] = 0;

    // staging coords: channel = tid>>4, x-offset = tid&15 (x fastest ->
    // coalesced 64B runs per 16 lanes)
    int scl = tid >> 4, scc = tid & 15;
    int sgx  = x0 + scc - 1;
    int sgxc = max(sgx, 0);                 // <= 126, always in-bounds
    float sfx = ((unsigned)sgx < WW) ? 1.f : 0.f;

    f32x4 acc[2][2];
    #pragma unroll
    for (int nt = 0; nt < 2; ++nt)
        #pragma unroll
        for (int mh = 0; mh < 2; ++mh)
            #pragma unroll
            for (int j = 0; j < 4; ++j) acc[nt][mh][j] = 0.f;

    for (int cg = 0; cg < 4; ++cg) {
        __syncthreads();                    // previous cg's reads done
        const float* I = inter + ((size_t)(b*CIN + cg*16))*HW;

        // main staging: rows r=0..9, cc=0..15 (2560 elems, 10/thread)
        {
            const float* colp = I + (size_t)scl*HW + sgxc;
            unsigned short* tp = til + scc*24 + scl;
            #pragma unroll
            for (int r = 0; r < 10; ++r) {
                int gy  = y0 + r - 1;
                int gyc = min(max(gy, 0), HH-1);
                float m = ((unsigned)gy < HH) ? sfx : 0.f;
                float v = colp[(size_t)gyc*WW] * m;
                tp[r*(18*24)] = f2bf(v);
            }
        }
        // tail staging: cc=16,17 (320 elems), i = r*32 + ccb*16 + cl
        #pragma unroll
        for (int k = 0; k < 2; ++k) {
            int i = k*256 + tid;
            if (i < 320) {
                int cl  = i & 15;
                int ccb = (i >> 4) & 1;         // cc = 16+ccb
                int r   = i >> 5;               // 0..9
                int gx  = x0 + 15 + ccb;
                int gy  = y0 + r - 1;
                int gxc = min(gx, WW-1);
                int gyc = min(max(gy, 0), HH-1);
                float m = (((unsigned)gy < HH) && ((unsigned)gx < WW)) ? 1.f : 0.f;
                float v = I[(size_t)cl*HW + gyc*WW + gxc] * m;
                til[(r*18 + 16 + ccb)*24 + cl] = f2bf(v);
            }
        }
        __syncthreads();

        #pragma unroll
        for (int ch = 0; ch < 5; ++ch) {
            short8 a0 = *(const short8*)(wk2 +
                (((size_t)(cg*5 + ch)*32 + nn)*32 + qq*8));
            short8 a1 = *(const short8*)(wk2 +
                (((size_t)(cg*5 + ch)*32 + 16 + nn)*32 + qq*8));
            int tap = ch*2 + (qq >> 1);
            #pragma unroll
            for (int nt = 0; nt < 2; ++nt) {
                int row = wv*2 + nt;            // 0..7
                int px_idx;
                if (tap > 8) px_idx = 180;
                else {
                    int ky = tap/3, kx = tap%3;
                    px_idx = (row + ky)*18 + (nn + kx);
                }
                short8 bfr = *(const short8*)(til + px_idx*24 + (qq&1)*8);
                acc[nt][0] = __builtin_amdgcn_mfma_f32_16x16x32_bf16(
                                 a0, bfr, acc[nt][0], 0, 0, 0);
                acc[nt][1] = __builtin_amdgcn_mfma_f32_16x16x32_bf16(
                                 a1, bfr, acc[nt][1], 0, 0, 0);
            }
        }
    }

    float* op = om + (size_t)b*27*HW;
    #pragma unroll
    for (int nt = 0; nt < 2; ++nt) {
        int pix = (y0 + wv*2 + nt)*WW + x0 + nn;
        #pragma unroll
        for (int mh = 0; mh < 2; ++mh)
            #pragma unroll
            for (int j = 0; j < 4; ++j) {
                int oc = mh*16 + qq*4 + j;
                if (oc < 27)
                    op[(size_t)oc*HW + pix] = acc[nt][mh][j] + com_b[oc];
            }
    }
}

// ---------------------------------------------------------------------------
// K2: conv (512) + w2 (576) + fT transpose (1024) = 2112 blocks
// ---------------------------------------------------------------------------
__global__ __launch_bounds__(256) void main2_kernel(
        const float* __restrict__ input_feat,
        const float* __restrict__ inter,
        const unsigned short* __restrict__ wk2,
        const float* __restrict__ com_b,
        const float* __restrict__ weight,
        const float* __restrict__ c2w,
        const float* __restrict__ c1w,
        const float* __restrict__ fea,
        float* __restrict__ om, unsigned short* __restrict__ w2b,
        unsigned short* __restrict__ fT) {
    __shared__ __align__(16) float smem[4416];
    int id = blockIdx.x, tid = threadIdx.x;
    if (id < 512)        conv_lds_body(id, tid, inter, wk2, com_b, om, smem);
    else if (id < 1088)  w2_body(id - 512, tid, weight, c2w, c1w, fea, w2b,
                                 smem, smem + 64*65);
    else                 transpose_body(input_feat, fT, id - 1088, tid, smem);
}

// ---------------------------------------------------------------------------
// K3: main DCN GEMM, bf16 MFMA, split-K across wave pairs.
// Byte-exact R8/R13 kernel (proven 52.7-53.0 us, best of 14 rounds).  The
// completed structure matrix (split/merged-K x LDS/global gathers, pack-vec,
// LDS-shrink, launch-bounds, barrier variants) shows this is the local
// optimum: split-K's duplicated scalar work fills the gather-latency shadow.
//  * XCD batch-binding (FETCH 13.6 -> 8.1 MB), 5-row swizzled LDS gather
//    window + global fallback, barrier-free loop, pk_fma +
//    v_cvt_pk_bf16_f32 pack, split-K reduce epilogue.
// ---------------------------------------------------------------------------
__global__ __launch_bounds__(256) void dcn_main_kernel(
        const unsigned short* __restrict__ fT,
        const unsigned short* __restrict__ w2b,
        const float* __restrict__ bias2,
        const float* __restrict__ om,
        float* __restrict__ out) {
    __shared__ __align__(16) unsigned short gtile[5*36*64];   // 23040 B
    int id = blockIdx.x;                 // 0..2047
    int xcd = id & 7;                    // round-robin XCD assignment
    int jj  = id >> 3;                   // 0..255 within this XCD
    int b   = xcd >> 1;                  // 2 XCDs per batch -> per-XCD L2 fit
    int y   = jj & 127;
    int xq  = ((xcd & 1) << 1) | (jj >> 7);   // 0..3 (bijective)

    int t = threadIdx.x;
    int lane = t & 63, wv = t >> 6;
    int strip = wv >> 1, kh = wv & 1;
    int nn = lane & 15, qq = lane >> 4;
    int px0 = xq*32 + strip*16;
    int x = px0 + nn;
    int pix = y*WW + x;
    const unsigned short* Fb = fT + (size_t)b*HW*64;
    const float* omb = om + (size_t)b*27*HW;
    const unsigned short* w2p = w2b + (size_t)(b*9)*4096 + kh*32 + qq*8;
    int co  = kh*32 + qq*8;       // element offset in a 64-ch pixel row
    int cob = kh*64 + qq*16;      // byte offset within a 128B pixel row

    // gather-tile window (always fully inside the image): rows [ybase,ybase+4]
    int ybase = min(max(y - 2, 0), HH - 5);        // [0,123]
    int xbase = min(max(xq*32 - 2, 0), WW - 36);   // [0,92]

    // stage 5x36 pixel rows = 1440 16B chunks, coalesced, swizzled
    char* gt = (char*)gtile;
    #pragma unroll
    for (int it = 0; it < 6; ++it) {
        int c = it*256 + t;
        if (c < 1440) {
            int pl = c >> 3;                    // local pixel 0..179
            int ci = c & 7;                     // 16B chunk in pixel
            int sy = (pl*1821) >> 16;           // pl/36 (exact for pl<216)
            int sx = pl - sy*36;
            short8 v = *(const short8*)(Fb +
                ((size_t)(ybase + sy)*WW + xbase + sx)*64 + ci*8);
            int bo = (pl*128 + ci*16) ^ ((pl & 7) << 4);
            *(short8*)(gt + bo) = v;
        }
    }

    f32x4 acc[4];
    #pragma unroll
    for (int mt = 0; mt < 4; ++mt)
        #pragma unroll
        for (int j = 0; j < 4; ++j)
            acc[mt][j] = kh ? bias2[mt*16 + qq*4 + j] : 0.f;

    float omy = omb[pix];
    float omx = omb[(size_t)HW + pix];
    float omm = omb[(size_t)18*HW + pix];
    __syncthreads();                             // tile ready

    #pragma unroll
    for (int p = 0; p < 9; ++p) {
        // A-frags for my K-half (tiny, L1/L2-hot)
        short8 afr[4];
        #pragma unroll
        for (int mt = 0; mt < 4; ++mt)
            afr[mt] = *(const short8*)(w2p + (size_t)p*4096 + (mt*16 + nn)*64);

        // bilinear corner weights for my pixel
        float mv = 1.f / (1.f + expf(-omm));
        float ysv = (float)(y - 1 + p/3) + omy;
        float xsv = (float)(x - 1 + p%3) + omx;
        float y0f = floorf(ysv), x0f = floorf(xsv);
        float ly = ysv - y0f, lx = xsv - x0f;
        int y0 = (int)y0f, x0i = (int)x0f;
        int y1 = y0 + 1, x1 = x0i + 1;
        float vy0 = (y0 >= 0 && y0 < HH) ? 1.f : 0.f;
        float vy1 = (y1 >= 0 && y1 < HH) ? 1.f : 0.f;
        float vx0 = (x0i >= 0 && x0i < WW) ? 1.f : 0.f;
        float vx1 = (x1 >= 0 && x1 < WW) ? 1.f : 0.f;
        float w00 = (1.f-ly)*(1.f-lx)*mv * vy0*vx0;
        float w01 = (1.f-ly)*lx      *mv * vy0*vx1;
        float w10 = ly      *(1.f-lx)*mv * vy1*vx0;
        float w11 = ly      *lx      *mv * vy1*vx1;
        int y0c = min(max(y0,0),HH-1), y1c = min(max(y1,0),HH-1);
        int x0c = min(max(x0i,0),WW-1), x1c = min(max(x1,0),WW-1);

        // prefetch next p's om
        if (p < 8) {
            omy = omb[(size_t)(2*p+2)*HW + pix];
            omx = omb[(size_t)(2*p+3)*HW + pix];
            omm = omb[(size_t)(19+p )*HW + pix];
        }

        // gather 4 corners: LDS fast path, global fallback (rare)
        short8 c00, c01, c10, c11;
        {
            int sy0 = y0c - ybase, sy1 = y1c - ybase;
            int sx0 = x0c - xbase, sx1 = x1c - xbase;
            bool allin = ((unsigned)sy0 < 5) & ((unsigned)sy1 < 5) &
                         ((unsigned)sx0 < 36) & ((unsigned)sx1 < 36);
            if (allin) {
                int p00 = sy0*36 + sx0, p01 = sy0*36 + sx1;
                int p10 = sy1*36 + sx0, p11 = sy1*36 + sx1;
                c00 = *(const short8*)(gt + ((p00*128 + cob) ^ ((p00&7)<<4)));
                c01 = *(const short8*)(gt + ((p01*128 + cob) ^ ((p01&7)<<4)));
                c10 = *(const short8*)(gt + ((p10*128 + cob) ^ ((p10&7)<<4)));
                c11 = *(const short8*)(gt + ((p11*128 + cob) ^ ((p11&7)<<4)));
            } else {
                int i00 = y0c*WW + x0c, i01 = y0c*WW + x1c;
                int i10 = y1c*WW + x0c, i11 = y1c*WW + x1c;
                c00 = *(const short8*)(Fb + (size_t)i00*64 + co);
                c01 = *(const short8*)(Fb + (size_t)i01*64 + co);
                c10 = *(const short8*)(Fb + (size_t)i10*64 + co);
                c11 = *(const short8*)(Fb + (size_t)i11*64 + co);
            }
        }

        // pack: float2 weighted sum (v_pk_fma_f32) + v_cvt_pk_bf16_f32
        uint4v u00 = __builtin_bit_cast(uint4v, c00);
        uint4v u01 = __builtin_bit_cast(uint4v, c01);
        uint4v u10 = __builtin_bit_cast(uint4v, c10);
        uint4v u11 = __builtin_bit_cast(uint4v, c11);
        unsigned int pw[4];
        #pragma unroll
        for (int jp = 0; jp < 4; ++jp) {
            f32x2 A = bfpair(u00[jp]);
            f32x2 B = bfpair(u01[jp]);
            f32x2 C = bfpair(u10[jp]);
            f32x2 D = bfpair(u11[jp]);
            f32x2 r = A*w00 + B*w01 + C*w10 + D*w11;
            pw[jp] = cvtpk_bf16(r[0], r[1]);
        }
        uint4v u4 = {pw[0], pw[1], pw[2], pw[3]};
        short8 bfr = __builtin_bit_cast(short8, u4);

        // MFMA (my K-half only)
        #pragma unroll
        for (int mt = 0; mt < 4; ++mt)
            acc[mt] = __builtin_amdgcn_mfma_f32_16x16x32_bf16(
                          afr[mt], bfr, acc[mt], 0, 0, 0);
    }

    // combine wave-pair partials; reduction buffer ALIASES gtile, so first
    // ensure all waves finished their LDS gathers.
    __syncthreads();
    float* red = (float*)gtile;
    if (kh == 0) {
        #pragma unroll
        for (int mt = 0; mt < 4; ++mt)
            #pragma unroll
            for (int j = 0; j < 4; ++j)
                red[(mt*4 + j)*128 + strip*64 + lane] = acc[mt][j];
    }
    __syncthreads();
    if (kh == 1) {
        float* outp = out + (size_t)b*COUT*HW + (size_t)y*WW + px0 + nn;
        #pragma unroll
        for (int mt = 0; mt < 4; ++mt)
            #pragma unroll
            for (int j = 0; j < 4; ++j)
                outp[(size_t)(mt*16 + qq*4 + j)*HW] =
                    acc[mt][j] + red[(mt*4 + j)*128 + strip*64 + lane];
    }
}

// ---------------------------------------------------------------------------
extern "C" void kernel_launch(void* const* d_in, const int* in_sizes, int n_in,
                              void* d_out, int out_size, void* d_ws, size_t ws_size,
                              hipStream_t stream) {
    const float* input_feat = (const float*)d_in[0];
    const float* inter      = (const float*)d_in[1];
    const float* fea        = (const float*)d_in[2];
    const float* weight     = (const float*)d_in[3];
    const float* bias       = (const float*)d_in[4];
    const float* com_w      = (const float*)d_in[5];
    const float* com_b      = (const float*)d_in[6];
    const float* c1w        = (const float*)d_in[7];
    const float* c2w        = (const float*)d_in[8];
    float* out = (float*)d_out;

    float* ws    = (float*)d_ws;
    float* bias2 = ws + 256;                               // 64 (in pad area)
    unsigned short* w2b = (unsigned short*)(ws + 512);     // 147456 us
    float* om    = ws + 512 + 73728;                       // 1769472 f
    unsigned short* wk2 = (unsigned short*)(om + 1769472); // 20480 us
    unsigned short* fT  = wk2 + 20480;                     // 4194304 us

    prep_kernel<<<81, 256, 0, stream>>>(com_w, c2w, bias, wk2, bias2);
    main2_kernel<<<2112, 256, 0, stream>>>(input_feat, inter, wk2, com_b,
                                           weight, c2w, c1w, fea, om, w2b, fT);
    dcn_main_kernel<<<2048, 256, 0, stream>>>(fT, w2b, bias2, om, out);
}